// Round 1
// 178.628 us; speedup vs baseline: 1.1491x; 1.1491x over previous
//
#include <hip/hip_runtime.h>

#define S_   4096
#define H_   1024
#define NH_  16
#define NT_  64                            // 64-key tiles
#define SCALE_LOG2E 0.18033688011112042f   // (1/8) * log2(e)

typedef __attribute__((ext_vector_type(8)))  short short8;
typedef __attribute__((ext_vector_type(16))) float f32x16;

__device__ __forceinline__ unsigned short f2bf(float x) {
    union { float f; unsigned u; } c; c.f = x;
    unsigned r = c.u + 0x7fffu + ((c.u >> 16) & 1u);   // RNE
    return (unsigned short)(r >> 16);
}
// RNE pack (cold paths: prepack, Q prologue)
__device__ __forceinline__ unsigned pk2(float a, float b) {
    return (unsigned)f2bf(a) | ((unsigned)f2bf(b) << 16);
}
// single-instruction truncating pack (hot path: P) — v_perm_b32
__device__ __forceinline__ unsigned pkt(float a, float b) {
    union { float f; unsigned u; } ca, cb; ca.f = a; cb.f = b;
    return __builtin_amdgcn_perm(cb.u, ca.u, 0x07060302u);  // [bf(b) : bf(a)]
}

// ---------------------------------------------------------------------------
// Prepass (LDS-free): fragment-major bf16 tile images, 4096 u16 per (hd,kt):
//   K''[kc][key][8] : kc = d>>3   (linear = kc*512 + key*8 + e)
//   V''[kc][d][8]   : kc = key>>3 (linear = kc*512 + d*8 + e)
// K path: thread -> (key=idx>>3, kc=idx&7): reads are 8 x 256B contiguous
// rows per wave (coalesced); writes land 128B-contiguous per 8-lane group
// (coalescer merges by address). V reads coalesced (lanes sweep d).
// ---------------------------------------------------------------------------
__global__ __launch_bounds__(256) void prepack(
    const float* __restrict__ k, const float* __restrict__ v,
    unsigned short* __restrict__ kp, unsigned short* __restrict__ vtp)
{
    const int t  = threadIdx.x;
    const int kt = blockIdx.x, hd = blockIdx.y;
    const size_t tb = ((size_t)hd * NT_ + kt) * 4096;
    uint4* gk = (uint4*)(kp + tb);
    uint4* gv = (uint4*)(vtp + tb);

    #pragma unroll
    for (int it = 0; it < 2; ++it) {
        int idx = t + 256 * it;
        {   // K'': coalesced row read, grouped-contiguous write
            int key = idx >> 3, kc = idx & 7;
            const float* src = k + (size_t)(kt * 64 + key) * H_ + hd * 64 + kc * 8;
            float4 a = *(const float4*)src;
            float4 b = *(const float4*)(src + 4);
            uint4 w;
            w.x = pk2(a.x, a.y); w.y = pk2(a.z, a.w);
            w.z = pk2(b.x, b.y); w.w = pk2(b.z, b.w);
            gk[kc * 64 + key] = w;
        }
        {   // V'': idx = kc*64 + d  (transpose gather, coalesced across lanes)
            int d = idx & 63, kc = idx >> 6;
            const float* src = v + (size_t)(kt * 64 + kc * 8) * H_ + hd * 64 + d;
            float p[8];
            #pragma unroll
            for (int j = 0; j < 8; ++j) p[j] = src[(size_t)j * H_];
            uint4 w;
            w.x = pk2(p[0], p[1]); w.y = pk2(p[2], p[3]);
            w.z = pk2(p[4], p[5]); w.w = pk2(p[6], p[7]);
            gv[idx] = w;
        }
    }
}

// ---------------------------------------------------------------------------
// Main: 256 threads = 4 waves; wave (qh = w>>1, kh = w&1) owns 32 qrows x
// 32-key half; 64 qrows/block, 1024 blocks, launch_bounds(256,3) -> 3
// blocks/CU (12 waves). Zero barriers in the K-loop. Register double-buffer
// of K and V fragments (tile t+1 prefetched during tile t) removes L2
// latency from the critical path; v_permlane32_swap_b32 replaces the
// xor-32 shfl + cndmask exchange (bit-identical A-fragments, no lgkm dep).
// ---------------------------------------------------------------------------
__global__ __launch_bounds__(256, 3) void attn_main(
    const float* __restrict__ q,
    const unsigned short* __restrict__ kp,
    const unsigned short* __restrict__ vtp,
    float* __restrict__ out)
{
    __shared__ __align__(16) float sO[2 * 2048];   // kh=1 partials, per qh
    __shared__ float sL[2 * 64];

    const int t   = threadIdx.x;
    const int b   = blockIdx.x;
    // XCD swizzle: 2 heads per XCD (2MB of K''+V'' resident per 4MB L2)
    const int xcd = b & 7;
    const int bi  = b >> 3;                 // 0..127
    const int hd  = xcd * 2 + (bi >> 6);
    const int qt  = bi & 63;                // 64 q-tiles of 64 rows

    const int w    = t >> 6;                // 0..3
    const int lane = t & 63;
    const int l31  = lane & 31;
    const int lhi  = lane >> 5;
    const int qh   = w >> 1;                // 0..1
    const int kh   = w & 1;

    const unsigned short* gK = kp  + (size_t)hd * NT_ * 4096;
    const unsigned short* gV = vtp + (size_t)hd * NT_ * 4096;

    // ---- Q fragments (B-operand), scaled, in registers ----
    short8 qf[4];
    {
        const float* qb = q + (size_t)(qt * 64 + qh * 32 + l31) * H_ + hd * 64 + lhi * 8;
        #pragma unroll
        for (int c = 0; c < 4; ++c) {
            float4 a  = *(const float4*)(qb + c * 16);
            float4 bb = *(const float4*)(qb + c * 16 + 4);
            union { short8 v; unsigned u[4]; } f;
            f.u[0] = pk2(a.x * SCALE_LOG2E, a.y * SCALE_LOG2E);
            f.u[1] = pk2(a.z * SCALE_LOG2E, a.w * SCALE_LOG2E);
            f.u[2] = pk2(bb.x * SCALE_LOG2E, bb.y * SCALE_LOG2E);
            f.u[3] = pk2(bb.z * SCALE_LOG2E, bb.w * SCALE_LOG2E);
            qf[c] = f.v;
        }
    }

    f32x16 Oacc[2];
    #pragma unroll
    for (int h = 0; h < 2; ++h)
        #pragma unroll
        for (int r = 0; r < 16; ++r) Oacc[h][r] = 0.0f;
    float2 ls2; ls2.x = 0.0f; ls2.y = 0.0f;

    // lane-invariant element offsets into a tile (u16 units)
    const int kOff = (kh * 32 + l31) * 8 + lhi * 512;     // + c*1024
    const int vOff = l31 * 8 + (kh * 4 + lhi) * 512;      // + c*1024 + h*256
    const unsigned short* pK = gK + kOff;
    const unsigned short* pV = gV + vOff;

    short8 kfA[4], vfA[4], kfB[4], vfB[4];

#define LOADF(KF, VF, tile)                                                  \
    {                                                                        \
        const unsigned short* kt_ = pK + (size_t)(tile) * 4096;              \
        const unsigned short* vt_ = pV + (size_t)(tile) * 4096;              \
        KF[0] = *(const short8*)(kt_);                                       \
        KF[1] = *(const short8*)(kt_ + 1024);                                \
        KF[2] = *(const short8*)(kt_ + 2048);                                \
        KF[3] = *(const short8*)(kt_ + 3072);                                \
        VF[0] = *(const short8*)(vt_);                                       \
        VF[1] = *(const short8*)(vt_ + 256);                                 \
        VF[2] = *(const short8*)(vt_ + 1024);                                \
        VF[3] = *(const short8*)(vt_ + 1280);                                \
    }

#define COMPUTE(KF, VF)                                                      \
    {                                                                        \
        f32x16 st;                                                           \
        _Pragma("unroll")                                                    \
        for (int r_ = 0; r_ < 16; ++r_) st[r_] = 0.0f;                       \
        st = __builtin_amdgcn_mfma_f32_32x32x16_bf16(KF[0], qf[0], st, 0, 0, 0); \
        st = __builtin_amdgcn_mfma_f32_32x32x16_bf16(KF[1], qf[1], st, 0, 0, 0); \
        st = __builtin_amdgcn_mfma_f32_32x32x16_bf16(KF[2], qf[2], st, 0, 0, 0); \
        st = __builtin_amdgcn_mfma_f32_32x32x16_bf16(KF[3], qf[3], st, 0, 0, 0); \
        unsigned pu[8];                                                      \
        _Pragma("unroll")                                                    \
        for (int i2_ = 0; i2_ < 8; ++i2_) {                                  \
            float p0 = __builtin_amdgcn_exp2f(st[2 * i2_]);                  \
            float p1 = __builtin_amdgcn_exp2f(st[2 * i2_ + 1]);              \
            ls2.x += p0; ls2.y += p1;                                        \
            pu[i2_] = pkt(p0, p1);                                           \
        }                                                                    \
        _Pragma("unroll")                                                    \
        for (int c_ = 0; c_ < 2; ++c_) {                                     \
            unsigned a0 = pu[4 * c_],     b0 = pu[4 * c_ + 2];               \
            unsigned a1 = pu[4 * c_ + 1], b1 = pu[4 * c_ + 3];               \
            /* a' = {a.lo, b.lo}; b' = {a.hi, b.hi} */                       \
            asm("v_permlane32_swap_b32 %0, %1" : "+v"(a0), "+v"(b0));        \
            asm("v_permlane32_swap_b32 %0, %1" : "+v"(a1), "+v"(b1));        \
            union { short8 v; unsigned u[4]; } pf;                           \
            pf.u[0] = a0; pf.u[1] = a1; pf.u[2] = b0; pf.u[3] = b1;          \
            Oacc[0] = __builtin_amdgcn_mfma_f32_32x32x16_bf16(pf.v, VF[2 * c_],     Oacc[0], 0, 0, 0); \
            Oacc[1] = __builtin_amdgcn_mfma_f32_32x32x16_bf16(pf.v, VF[2 * c_ + 1], Oacc[1], 0, 0, 0); \
        }                                                                    \
    }

    // ---- software-pipelined K-loop: prefetch tile t+1 while computing t ----
    LOADF(kfA, vfA, 0);
    for (int kt2 = 0; kt2 < 31; ++kt2) {
        LOADF(kfB, vfB, 2 * kt2 + 1);
        COMPUTE(kfA, vfA);
        LOADF(kfA, vfA, 2 * kt2 + 2);
        COMPUTE(kfB, vfB);
    }
    LOADF(kfB, vfB, 63);
    COMPUTE(kfA, vfA);
    COMPUTE(kfB, vfB);

#undef LOADF
#undef COMPUTE

    // ---- epilogue: combine kh halves, normalize, store ----
    float lsum = ls2.x + ls2.y;
    lsum += __shfl_xor(lsum, 32);
    if (lhi == 0) sL[kh * 64 + qh * 32 + l31] = lsum;
    if (kh == 1) {
        float* o = sO + qh * 2048;
        #pragma unroll
        for (int h = 0; h < 2; ++h)
            #pragma unroll
            for (int r = 0; r < 16; ++r)
                o[h * 1024 + r * 64 + lane] = Oacc[h][r];
    }
    __syncthreads();
    if (kh == 0) {
        float linv[4][4];
        #pragma unroll
        for (int qd = 0; qd < 4; ++qd) {
            int base = qh * 32 + 8 * qd + 4 * lhi;
            float4 a  = *(const float4*)(sL + base);
            float4 bb = *(const float4*)(sL + 64 + base);
            linv[qd][0] = __builtin_amdgcn_rcpf(a.x + bb.x);
            linv[qd][1] = __builtin_amdgcn_rcpf(a.y + bb.y);
            linv[qd][2] = __builtin_amdgcn_rcpf(a.z + bb.z);
            linv[qd][3] = __builtin_amdgcn_rcpf(a.w + bb.w);
        }
        const float* o = sO + qh * 2048;
        #pragma unroll
        for (int h = 0; h < 2; ++h)
            #pragma unroll
            for (int qd = 0; qd < 4; ++qd)
                #pragma unroll
                for (int e = 0; e < 4; ++e) {
                    int r   = 4 * qd + e;
                    int row = qh * 32 + e + 8 * qd + 4 * lhi;
                    float val = (Oacc[h][r] + o[h * 1024 + r * 64 + lane]) * linv[qd][e];
                    out[(size_t)(qt * 64 + row) * H_ + hd * 64 + h * 32 + l31] = val;
                }
    }
}

extern "C" void kernel_launch(void* const* d_in, const int* in_sizes, int n_in,
                              void* d_out, int out_size, void* d_ws, size_t ws_size,
                              hipStream_t stream) {
    const float* q = (const float*)d_in[0];
    const float* k = (const float*)d_in[1];
    const float* v = (const float*)d_in[2];
    float* out = (float*)d_out;

    unsigned short* kp  = (unsigned short*)d_ws;                 // 8 MB
    unsigned short* vtp = kp + (size_t)NH_ * NT_ * 4096;         // 8 MB

    prepack<<<dim3(NT_, NH_), 256, 0, stream>>>(k, v, kp, vtp);
    attn_main<<<dim3(1024), 256, 0, stream>>>(q, kp, vtp, out);
}

// Round 2
// 164.702 us; speedup vs baseline: 1.2462x; 1.0846x over previous
//
#include <hip/hip_runtime.h>

#define S_   4096
#define H_   1024
#define NH_  16
#define NT_  64                            // 64-key tiles
#define SCALE_LOG2E 0.18033688011112042f   // (1/8) * log2(e)

typedef __attribute__((ext_vector_type(8)))  short short8;
typedef __attribute__((ext_vector_type(16))) float f32x16;

__device__ __forceinline__ unsigned short f2bf(float x) {
    union { float f; unsigned u; } c; c.f = x;
    unsigned r = c.u + 0x7fffu + ((c.u >> 16) & 1u);   // RNE
    return (unsigned short)(r >> 16);
}
// RNE pack (cold paths: prepack, Q prologue)
__device__ __forceinline__ unsigned pk2(float a, float b) {
    return (unsigned)f2bf(a) | ((unsigned)f2bf(b) << 16);
}
// single-instruction truncating pack (hot path: P) — v_perm_b32
__device__ __forceinline__ unsigned pkt(float a, float b) {
    union { float f; unsigned u; } ca, cb; ca.f = a; cb.f = b;
    return __builtin_amdgcn_perm(cb.u, ca.u, 0x07060302u);  // [bf(b) : bf(a)]
}

// ---------------------------------------------------------------------------
// Prepass (LDS-free): fragment-major bf16 tile images, 4096 u16 per (hd,kt):
//   K''[kc][key][8] : kc = d>>3   (linear = kc*512 + key*8 + e)
//   V''[kc][d][8]   : kc = key>>3 (linear = kc*512 + d*8 + e)
// ---------------------------------------------------------------------------
__global__ __launch_bounds__(256) void prepack(
    const float* __restrict__ k, const float* __restrict__ v,
    unsigned short* __restrict__ kp, unsigned short* __restrict__ vtp)
{
    const int t  = threadIdx.x;
    const int kt = blockIdx.x, hd = blockIdx.y;
    const size_t tb = ((size_t)hd * NT_ + kt) * 4096;
    uint4* gk = (uint4*)(kp + tb);
    uint4* gv = (uint4*)(vtp + tb);

    #pragma unroll
    for (int it = 0; it < 2; ++it) {
        int idx = t + 256 * it;
        {   // K'': coalesced row read, grouped-contiguous write
            int key = idx >> 3, kc = idx & 7;
            const float* src = k + (size_t)(kt * 64 + key) * H_ + hd * 64 + kc * 8;
            float4 a = *(const float4*)src;
            float4 b = *(const float4*)(src + 4);
            uint4 w;
            w.x = pk2(a.x, a.y); w.y = pk2(a.z, a.w);
            w.z = pk2(b.x, b.y); w.w = pk2(b.z, b.w);
            gk[kc * 64 + key] = w;
        }
        {   // V'': idx = kc*64 + d  (transpose gather, coalesced across lanes)
            int d = idx & 63, kc = idx >> 6;
            const float* src = v + (size_t)(kt * 64 + kc * 8) * H_ + hd * 64 + d;
            float p[8];
            #pragma unroll
            for (int j = 0; j < 8; ++j) p[j] = src[(size_t)j * H_];
            uint4 w;
            w.x = pk2(p[0], p[1]); w.y = pk2(p[2], p[3]);
            w.z = pk2(p[4], p[5]); w.w = pk2(p[6], p[7]);
            gv[idx] = w;
        }
    }
}

// ---------------------------------------------------------------------------
// Main: 256 threads = 4 waves; wave (qg = w>>1, kh = w&1) owns 64 qrows x
// 32-key half (two 32-row MFMA groups s=0,1 sharing the SAME K/V fragment
// loads -> 64 FLOP/byte from L2, 2x the reuse of the 32-row version).
// 128 qrows/block, 512 blocks = exactly 2 blocks/CU, ALL resident (no tail).
// Zero barriers in the K-loop; register double-buffer of K+V fragments;
// v_permlane32_swap_b32 exchange; loop-invariant zero C-operand; setprio
// around MFMA clusters.
// ---------------------------------------------------------------------------
__global__ __launch_bounds__(256, 2) void attn_main(
    const float* __restrict__ q,
    const unsigned short* __restrict__ kp,
    const unsigned short* __restrict__ vtp,
    float* __restrict__ out)
{
    __shared__ __align__(16) float sO[4 * 2048];   // kh=1 partials, per (qg,s)
    __shared__ float sL[2 * 128];

    const int t   = threadIdx.x;
    const int b   = blockIdx.x;
    // XCD swizzle: 2 heads per XCD (2MB of K''+V'' resident per 4MB L2)
    const int xcd = b & 7;
    const int bi  = b >> 3;                 // 0..63
    const int hd  = xcd * 2 + (bi >> 5);
    const int qt  = bi & 31;                // 32 q-tiles of 128 rows

    const int w    = t >> 6;                // 0..3
    const int lane = t & 63;
    const int l31  = lane & 31;
    const int lhi  = lane >> 5;
    const int qg   = w >> 1;                // 0..1 (64-row q group)
    const int kh   = w & 1;

    const unsigned short* gK = kp  + (size_t)hd * NT_ * 4096;
    const unsigned short* gV = vtp + (size_t)hd * NT_ * 4096;

    // ---- Q fragments (B-operand), scaled, in registers: 2 x 32-row sets ----
    short8 qf[2][4];
    #pragma unroll
    for (int s = 0; s < 2; ++s) {
        const float* qb = q + (size_t)(qt * 128 + qg * 64 + s * 32 + l31) * H_ + hd * 64 + lhi * 8;
        #pragma unroll
        for (int c = 0; c < 4; ++c) {
            float4 a  = *(const float4*)(qb + c * 16);
            float4 bb = *(const float4*)(qb + c * 16 + 4);
            union { short8 v; unsigned u[4]; } f;
            f.u[0] = pk2(a.x * SCALE_LOG2E, a.y * SCALE_LOG2E);
            f.u[1] = pk2(a.z * SCALE_LOG2E, a.w * SCALE_LOG2E);
            f.u[2] = pk2(bb.x * SCALE_LOG2E, bb.y * SCALE_LOG2E);
            f.u[3] = pk2(bb.z * SCALE_LOG2E, bb.w * SCALE_LOG2E);
            qf[s][c] = f.v;
        }
    }

    f32x16 Oacc[2][2];
    #pragma unroll
    for (int s = 0; s < 2; ++s)
        #pragma unroll
        for (int h = 0; h < 2; ++h)
            #pragma unroll
            for (int r = 0; r < 16; ++r) Oacc[s][h][r] = 0.0f;
    float2 ls[2];
    ls[0].x = 0.0f; ls[0].y = 0.0f; ls[1].x = 0.0f; ls[1].y = 0.0f;

    // loop-invariant zero C-operand (init'd once, not per tile)
    f32x16 zero16;
    #pragma unroll
    for (int r = 0; r < 16; ++r) zero16[r] = 0.0f;

    // lane-invariant element offsets into a tile (u16 units)
    const int kOff = (kh * 32 + l31) * 8 + lhi * 512;     // + c*1024
    const int vOff = l31 * 8 + (kh * 4 + lhi) * 512;      // + c*1024 + h*256
    const unsigned short* pK = gK + kOff;
    const unsigned short* pV = gV + vOff;

    short8 kfA[4], vfA[4], kfB[4], vfB[4];

#define LOADF(KF, VF, tile)                                                  \
    {                                                                        \
        const unsigned short* kt_ = pK + (size_t)(tile) * 4096;              \
        const unsigned short* vt_ = pV + (size_t)(tile) * 4096;              \
        KF[0] = *(const short8*)(kt_);                                       \
        KF[1] = *(const short8*)(kt_ + 1024);                                \
        KF[2] = *(const short8*)(kt_ + 2048);                                \
        KF[3] = *(const short8*)(kt_ + 3072);                                \
        VF[0] = *(const short8*)(vt_);                                       \
        VF[1] = *(const short8*)(vt_ + 256);                                 \
        VF[2] = *(const short8*)(vt_ + 1024);                                \
        VF[3] = *(const short8*)(vt_ + 1280);                                \
    }

#define COMPUTE(KF, VF)                                                      \
    {                                                                        \
        _Pragma("unroll")                                                    \
        for (int s_ = 0; s_ < 2; ++s_) {                                     \
            __builtin_amdgcn_s_setprio(1);                                   \
            f32x16 st = __builtin_amdgcn_mfma_f32_32x32x16_bf16(KF[0], qf[s_][0], zero16, 0, 0, 0); \
            st = __builtin_amdgcn_mfma_f32_32x32x16_bf16(KF[1], qf[s_][1], st, 0, 0, 0); \
            st = __builtin_amdgcn_mfma_f32_32x32x16_bf16(KF[2], qf[s_][2], st, 0, 0, 0); \
            st = __builtin_amdgcn_mfma_f32_32x32x16_bf16(KF[3], qf[s_][3], st, 0, 0, 0); \
            __builtin_amdgcn_s_setprio(0);                                   \
            unsigned pu[8];                                                  \
            _Pragma("unroll")                                                \
            for (int i2_ = 0; i2_ < 8; ++i2_) {                              \
                float p0 = __builtin_amdgcn_exp2f(st[2 * i2_]);              \
                float p1 = __builtin_amdgcn_exp2f(st[2 * i2_ + 1]);          \
                ls[s_].x += p0; ls[s_].y += p1;                              \
                pu[i2_] = pkt(p0, p1);                                       \
            }                                                                \
            _Pragma("unroll")                                                \
            for (int c_ = 0; c_ < 2; ++c_) {                                 \
                unsigned a0 = pu[4 * c_],     b0 = pu[4 * c_ + 2];           \
                unsigned a1 = pu[4 * c_ + 1], b1 = pu[4 * c_ + 3];           \
                /* a' = {a.lo, b.lo}; b' = {a.hi, b.hi} */                   \
                asm("v_permlane32_swap_b32 %0, %1" : "+v"(a0), "+v"(b0));    \
                asm("v_permlane32_swap_b32 %0, %1" : "+v"(a1), "+v"(b1));    \
                union { short8 v; unsigned u[4]; } pf;                       \
                pf.u[0] = a0; pf.u[1] = a1; pf.u[2] = b0; pf.u[3] = b1;      \
                __builtin_amdgcn_s_setprio(1);                               \
                Oacc[s_][0] = __builtin_amdgcn_mfma_f32_32x32x16_bf16(pf.v, VF[2 * c_],     Oacc[s_][0], 0, 0, 0); \
                Oacc[s_][1] = __builtin_amdgcn_mfma_f32_32x32x16_bf16(pf.v, VF[2 * c_ + 1], Oacc[s_][1], 0, 0, 0); \
                __builtin_amdgcn_s_setprio(0);                               \
            }                                                                \
        }                                                                    \
    }

    // ---- software-pipelined K-loop: prefetch tile t+1 while computing t ----
    LOADF(kfA, vfA, 0);
    for (int kt2 = 0; kt2 < 31; ++kt2) {
        LOADF(kfB, vfB, 2 * kt2 + 1);
        COMPUTE(kfA, vfA);
        LOADF(kfA, vfA, 2 * kt2 + 2);
        COMPUTE(kfB, vfB);
    }
    LOADF(kfB, vfB, 63);
    COMPUTE(kfA, vfA);
    COMPUTE(kfB, vfB);

#undef LOADF
#undef COMPUTE

    // ---- epilogue: combine kh halves, normalize, store ----
    #pragma unroll
    for (int s = 0; s < 2; ++s) {
        float lsum = ls[s].x + ls[s].y;
        lsum += __shfl_xor(lsum, 32);
        if (lhi == 0) sL[kh * 128 + qg * 64 + s * 32 + l31] = lsum;
    }
    if (kh == 1) {
        #pragma unroll
        for (int s = 0; s < 2; ++s) {
            float* o = sO + (qg * 2 + s) * 2048;
            #pragma unroll
            for (int h = 0; h < 2; ++h)
                #pragma unroll
                for (int r = 0; r < 16; ++r)
                    o[h * 1024 + r * 64 + lane] = Oacc[s][h][r];
        }
    }
    __syncthreads();
    if (kh == 0) {
        #pragma unroll
        for (int s = 0; s < 2; ++s) {
            float linv[4][4];
            #pragma unroll
            for (int qd = 0; qd < 4; ++qd) {
                int base = qg * 64 + s * 32 + 8 * qd + 4 * lhi;
                float4 a  = *(const float4*)(sL + base);
                float4 bb = *(const float4*)(sL + 128 + base);
                linv[qd][0] = __builtin_amdgcn_rcpf(a.x + bb.x);
                linv[qd][1] = __builtin_amdgcn_rcpf(a.y + bb.y);
                linv[qd][2] = __builtin_amdgcn_rcpf(a.z + bb.z);
                linv[qd][3] = __builtin_amdgcn_rcpf(a.w + bb.w);
            }
            const float* o = sO + (qg * 2 + s) * 2048;
            #pragma unroll
            for (int h = 0; h < 2; ++h)
                #pragma unroll
                for (int qd = 0; qd < 4; ++qd)
                    #pragma unroll
                    for (int e = 0; e < 4; ++e) {
                        int r   = 4 * qd + e;
                        int row = e + 8 * qd + 4 * lhi;
                        float val = (Oacc[s][h][r] + o[h * 1024 + r * 64 + lane]) * linv[qd][e];
                        out[(size_t)(qt * 128 + qg * 64 + s * 32 + row) * H_ + hd * 64 + h * 32 + l31] = val;
                    }
        }
    }
}

extern "C" void kernel_launch(void* const* d_in, const int* in_sizes, int n_in,
                              void* d_out, int out_size, void* d_ws, size_t ws_size,
                              hipStream_t stream) {
    const float* q = (const float*)d_in[0];
    const float* k = (const float*)d_in[1];
    const float* v = (const float*)d_in[2];
    float* out = (float*)d_out;

    unsigned short* kp  = (unsigned short*)d_ws;                 // 8 MB
    unsigned short* vtp = kp + (size_t)NH_ * NT_ * 4096;         // 8 MB

    prepack<<<dim3(NT_, NH_), 256, 0, stream>>>(k, v, kp, vtp);
    attn_main<<<dim3(512), 256, 0, stream>>>(q, kp, vtp, out);
}

// Round 3
// 162.774 us; speedup vs baseline: 1.2610x; 1.0118x over previous
//
#include <hip/hip_runtime.h>

#define S_   4096
#define H_   1024
#define NH_  16
#define NT_  64                            // 64-key tiles
#define SCALE_LOG2E 0.18033688011112042f   // (1/8) * log2(e)

typedef __attribute__((ext_vector_type(8)))  short short8;
typedef __attribute__((ext_vector_type(16))) float f32x16;

__device__ __forceinline__ unsigned short f2bf(float x) {
    union { float f; unsigned u; } c; c.f = x;
    unsigned r = c.u + 0x7fffu + ((c.u >> 16) & 1u);   // RNE
    return (unsigned short)(r >> 16);
}
// RNE pack (cold paths: prepack, Q prologue)
__device__ __forceinline__ unsigned pk2(float a, float b) {
    return (unsigned)f2bf(a) | ((unsigned)f2bf(b) << 16);
}
// single-instruction truncating pack (hot path: P) — v_perm_b32
__device__ __forceinline__ unsigned pkt(float a, float b) {
    union { float f; unsigned u; } ca, cb; ca.f = a; cb.f = b;
    return __builtin_amdgcn_perm(cb.u, ca.u, 0x07060302u);  // [bf(b) : bf(a)]
}

// ---------------------------------------------------------------------------
// Prepass (LDS-free): fragment-major bf16 tile images, 4096 u16 per (hd,kt):
//   K''[kc][key][8] : kc = d>>3   (linear = kc*512 + key*8 + e)
//   V''[kc][d][8]   : kc = key>>3 (linear = kc*512 + d*8 + e)
// ---------------------------------------------------------------------------
__global__ __launch_bounds__(256) void prepack(
    const float* __restrict__ k, const float* __restrict__ v,
    unsigned short* __restrict__ kp, unsigned short* __restrict__ vtp)
{
    const int t  = threadIdx.x;
    const int kt = blockIdx.x, hd = blockIdx.y;
    const size_t tb = ((size_t)hd * NT_ + kt) * 4096;
    uint4* gk = (uint4*)(kp + tb);
    uint4* gv = (uint4*)(vtp + tb);

    #pragma unroll
    for (int it = 0; it < 2; ++it) {
        int idx = t + 256 * it;
        {   // K'': coalesced row read, grouped-contiguous write
            int key = idx >> 3, kc = idx & 7;
            const float* src = k + (size_t)(kt * 64 + key) * H_ + hd * 64 + kc * 8;
            float4 a = *(const float4*)src;
            float4 b = *(const float4*)(src + 4);
            uint4 w;
            w.x = pk2(a.x, a.y); w.y = pk2(a.z, a.w);
            w.z = pk2(b.x, b.y); w.w = pk2(b.z, b.w);
            gk[kc * 64 + key] = w;
        }
        {   // V'': idx = kc*64 + d  (transpose gather, coalesced across lanes)
            int d = idx & 63, kc = idx >> 6;
            const float* src = v + (size_t)(kt * 64 + kc * 8) * H_ + hd * 64 + d;
            float p[8];
            #pragma unroll
            for (int j = 0; j < 8; ++j) p[j] = src[(size_t)j * H_];
            uint4 w;
            w.x = pk2(p[0], p[1]); w.y = pk2(p[2], p[3]);
            w.z = pk2(p[4], p[5]); w.w = pk2(p[6], p[7]);
            gv[idx] = w;
        }
    }
}

// ---------------------------------------------------------------------------
// Main: 256 threads = 4 waves; wave (qg = w>>1, kh = w&1) owns 64 qrows x
// 32-key half (two 32-row groups s=0,1 sharing the SAME K/V fragment loads
// -> 64 FLOP/byte from L2). 128 qrows/block, 512 blocks = exactly 2
// blocks/CU, all resident. Zero barriers in the K-loop; register
// double-buffer of K+V fragments; v_permlane32_swap_b32 exchange.
// NO setprio and NO scheduling fences in the body: both s-groups' QK
// chains are issued interleaved, and SM/PV phases are left free for the
// scheduler to cross-slide (s1's exp chain hides under s0's PV latency).
// ---------------------------------------------------------------------------
__global__ __launch_bounds__(256, 2) void attn_main(
    const float* __restrict__ q,
    const unsigned short* __restrict__ kp,
    const unsigned short* __restrict__ vtp,
    float* __restrict__ out)
{
    __shared__ __align__(16) float sO[4 * 2048];   // kh=1 partials, per (qg,s)
    __shared__ float sL[2 * 128];

    const int t   = threadIdx.x;
    const int b   = blockIdx.x;
    // XCD swizzle: 2 heads per XCD (2MB of K''+V'' resident per 4MB L2)
    const int xcd = b & 7;
    const int bi  = b >> 3;                 // 0..63
    const int hd  = xcd * 2 + (bi >> 5);
    const int qt  = bi & 31;                // 32 q-tiles of 128 rows

    const int w    = t >> 6;                // 0..3
    const int lane = t & 63;
    const int l31  = lane & 31;
    const int lhi  = lane >> 5;
    const int qg   = w >> 1;                // 0..1 (64-row q group)
    const int kh   = w & 1;

    const unsigned short* gK = kp  + (size_t)hd * NT_ * 4096;
    const unsigned short* gV = vtp + (size_t)hd * NT_ * 4096;

    // ---- Q fragments (B-operand), scaled, in registers: 2 x 32-row sets ----
    short8 qf[2][4];
    #pragma unroll
    for (int s = 0; s < 2; ++s) {
        const float* qb = q + (size_t)(qt * 128 + qg * 64 + s * 32 + l31) * H_ + hd * 64 + lhi * 8;
        #pragma unroll
        for (int c = 0; c < 4; ++c) {
            float4 a  = *(const float4*)(qb + c * 16);
            float4 bb = *(const float4*)(qb + c * 16 + 4);
            union { short8 v; unsigned u[4]; } f;
            f.u[0] = pk2(a.x * SCALE_LOG2E, a.y * SCALE_LOG2E);
            f.u[1] = pk2(a.z * SCALE_LOG2E, a.w * SCALE_LOG2E);
            f.u[2] = pk2(bb.x * SCALE_LOG2E, bb.y * SCALE_LOG2E);
            f.u[3] = pk2(bb.z * SCALE_LOG2E, bb.w * SCALE_LOG2E);
            qf[s][c] = f.v;
        }
    }

    f32x16 Oacc[2][2];
    #pragma unroll
    for (int s = 0; s < 2; ++s)
        #pragma unroll
        for (int h = 0; h < 2; ++h)
            #pragma unroll
            for (int r = 0; r < 16; ++r) Oacc[s][h][r] = 0.0f;
    float2 ls[2];
    ls[0].x = 0.0f; ls[0].y = 0.0f; ls[1].x = 0.0f; ls[1].y = 0.0f;

    // loop-invariant zero C-operand (init'd once, not per tile)
    f32x16 zero16;
    #pragma unroll
    for (int r = 0; r < 16; ++r) zero16[r] = 0.0f;

    // lane-invariant element offsets into a tile (u16 units)
    const int kOff = (kh * 32 + l31) * 8 + lhi * 512;     // + c*1024
    const int vOff = l31 * 8 + (kh * 4 + lhi) * 512;      // + c*1024 + h*256
    const unsigned short* pK = gK + kOff;
    const unsigned short* pV = gV + vOff;

    short8 kfA[4], vfA[4], kfB[4], vfB[4];

#define LOADF(KF, VF, tile)                                                  \
    {                                                                        \
        const unsigned short* kt_ = pK + (size_t)(tile) * 4096;              \
        const unsigned short* vt_ = pV + (size_t)(tile) * 4096;              \
        KF[0] = *(const short8*)(kt_);                                       \
        KF[1] = *(const short8*)(kt_ + 1024);                                \
        KF[2] = *(const short8*)(kt_ + 2048);                                \
        KF[3] = *(const short8*)(kt_ + 3072);                                \
        VF[0] = *(const short8*)(vt_);                                       \
        VF[1] = *(const short8*)(vt_ + 256);                                 \
        VF[2] = *(const short8*)(vt_ + 1024);                                \
        VF[3] = *(const short8*)(vt_ + 1280);                                \
    }

// softmax of one s-group: 16 exp2 + lsum + trunc-pack
#define SMAX(ST, LS, PU)                                                     \
    {                                                                        \
        _Pragma("unroll")                                                    \
        for (int i2_ = 0; i2_ < 8; ++i2_) {                                  \
            float p0 = __builtin_amdgcn_exp2f(ST[2 * i2_]);                  \
            float p1 = __builtin_amdgcn_exp2f(ST[2 * i2_ + 1]);              \
            LS.x += p0; LS.y += p1;                                          \
            PU[i2_] = pkt(p0, p1);                                           \
        }                                                                    \
    }

// PV of one s-group: permlane exchange + 4 MFMA
#define PVAC(PU, VF, OA)                                                     \
    {                                                                        \
        _Pragma("unroll")                                                    \
        for (int c_ = 0; c_ < 2; ++c_) {                                     \
            unsigned a0 = PU[4 * c_],     b0 = PU[4 * c_ + 2];               \
            unsigned a1 = PU[4 * c_ + 1], b1 = PU[4 * c_ + 3];               \
            /* a' = {a.lo, b.lo}; b' = {a.hi, b.hi} */                       \
            asm("v_permlane32_swap_b32 %0, %1" : "+v"(a0), "+v"(b0));        \
            asm("v_permlane32_swap_b32 %0, %1" : "+v"(a1), "+v"(b1));        \
            union { short8 v; unsigned u[4]; } pf;                           \
            pf.u[0] = a0; pf.u[1] = a1; pf.u[2] = b0; pf.u[3] = b1;          \
            OA[0] = __builtin_amdgcn_mfma_f32_32x32x16_bf16(pf.v, VF[2 * c_],     OA[0], 0, 0, 0); \
            OA[1] = __builtin_amdgcn_mfma_f32_32x32x16_bf16(pf.v, VF[2 * c_ + 1], OA[1], 0, 0, 0); \
        }                                                                    \
    }

#define COMPUTE(KF, VF)                                                      \
    {                                                                        \
        /* both QK chains interleaved: independent work back-to-back */      \
        f32x16 st0 = __builtin_amdgcn_mfma_f32_32x32x16_bf16(KF[0], qf[0][0], zero16, 0, 0, 0); \
        f32x16 st1 = __builtin_amdgcn_mfma_f32_32x32x16_bf16(KF[0], qf[1][0], zero16, 0, 0, 0); \
        st0 = __builtin_amdgcn_mfma_f32_32x32x16_bf16(KF[1], qf[0][1], st0, 0, 0, 0); \
        st1 = __builtin_amdgcn_mfma_f32_32x32x16_bf16(KF[1], qf[1][1], st1, 0, 0, 0); \
        st0 = __builtin_amdgcn_mfma_f32_32x32x16_bf16(KF[2], qf[0][2], st0, 0, 0, 0); \
        st1 = __builtin_amdgcn_mfma_f32_32x32x16_bf16(KF[2], qf[1][2], st1, 0, 0, 0); \
        st0 = __builtin_amdgcn_mfma_f32_32x32x16_bf16(KF[3], qf[0][3], st0, 0, 0, 0); \
        st1 = __builtin_amdgcn_mfma_f32_32x32x16_bf16(KF[3], qf[1][3], st1, 0, 0, 0); \
        unsigned pu0[8], pu1[8];                                             \
        SMAX(st0, ls[0], pu0);                                               \
        PVAC(pu0, VF, Oacc[0]);                                              \
        SMAX(st1, ls[1], pu1);                                               \
        PVAC(pu1, VF, Oacc[1]);                                              \
    }

    // ---- software-pipelined K-loop: prefetch tile t+1 while computing t ----
    LOADF(kfA, vfA, 0);
    for (int kt2 = 0; kt2 < 31; ++kt2) {
        LOADF(kfB, vfB, 2 * kt2 + 1);
        COMPUTE(kfA, vfA);
        LOADF(kfA, vfA, 2 * kt2 + 2);
        COMPUTE(kfB, vfB);
    }
    LOADF(kfB, vfB, 63);
    COMPUTE(kfA, vfA);
    COMPUTE(kfB, vfB);

#undef LOADF
#undef SMAX
#undef PVAC
#undef COMPUTE

    // ---- epilogue: combine kh halves, normalize, store ----
    #pragma unroll
    for (int s = 0; s < 2; ++s) {
        float lsum = ls[s].x + ls[s].y;
        lsum += __shfl_xor(lsum, 32);
        if (lhi == 0) sL[kh * 128 + qg * 64 + s * 32 + l31] = lsum;
    }
    if (kh == 1) {
        #pragma unroll
        for (int s = 0; s < 2; ++s) {
            float* o = sO + (qg * 2 + s) * 2048;
            #pragma unroll
            for (int h = 0; h < 2; ++h)
                #pragma unroll
                for (int r = 0; r < 16; ++r)
                    o[h * 1024 + r * 64 + lane] = Oacc[s][h][r];
        }
    }
    __syncthreads();
    if (kh == 0) {
        #pragma unroll
        for (int s = 0; s < 2; ++s) {
            float linv[4][4];
            #pragma unroll
            for (int qd = 0; qd < 4; ++qd) {
                int base = qg * 64 + s * 32 + 8 * qd + 4 * lhi;
                float4 a  = *(const float4*)(sL + base);
                float4 bb = *(const float4*)(sL + 128 + base);
                linv[qd][0] = __builtin_amdgcn_rcpf(a.x + bb.x);
                linv[qd][1] = __builtin_amdgcn_rcpf(a.y + bb.y);
                linv[qd][2] = __builtin_amdgcn_rcpf(a.z + bb.z);
                linv[qd][3] = __builtin_amdgcn_rcpf(a.w + bb.w);
            }
            const float* o = sO + (qg * 2 + s) * 2048;
            #pragma unroll
            for (int h = 0; h < 2; ++h)
                #pragma unroll
                for (int qd = 0; qd < 4; ++qd)
                    #pragma unroll
                    for (int e = 0; e < 4; ++e) {
                        int r   = 4 * qd + e;
                        int row = e + 8 * qd + 4 * lhi;
                        float val = (Oacc[s][h][r] + o[h * 1024 + r * 64 + lane]) * linv[qd][e];
                        out[(size_t)(qt * 128 + qg * 64 + s * 32 + row) * H_ + hd * 64 + h * 32 + l31] = val;
                    }
        }
    }
}

extern "C" void kernel_launch(void* const* d_in, const int* in_sizes, int n_in,
                              void* d_out, int out_size, void* d_ws, size_t ws_size,
                              hipStream_t stream) {
    const float* q = (const float*)d_in[0];
    const float* k = (const float*)d_in[1];
    const float* v = (const float*)d_in[2];
    float* out = (float*)d_out;

    unsigned short* kp  = (unsigned short*)d_ws;                 // 8 MB
    unsigned short* vtp = kp + (size_t)NH_ * NT_ * 4096;         // 8 MB

    prepack<<<dim3(NT_, NH_), 256, 0, stream>>>(k, v, kp, vtp);
    attn_main<<<dim3(512), 256, 0, stream>>>(q, kp, vtp, out);
}

// Round 5
// 161.467 us; speedup vs baseline: 1.2712x; 1.0081x over previous
//
#include <hip/hip_runtime.h>

#define S_   4096
#define H_   1024
#define NH_  16
#define NT_  64                            // 64-key tiles
#define SCALE_LOG2E 0.18033688011112042f   // (1/8) * log2(e)

typedef __attribute__((ext_vector_type(8)))  short short8;
typedef __attribute__((ext_vector_type(16))) float f32x16;

__device__ __forceinline__ unsigned short f2bf(float x) {
    union { float f; unsigned u; } c; c.f = x;
    unsigned r = c.u + 0x7fffu + ((c.u >> 16) & 1u);   // RNE
    return (unsigned short)(r >> 16);
}
// RNE pack (cold paths: prepack, Q prologue)
__device__ __forceinline__ unsigned pk2(float a, float b) {
    return (unsigned)f2bf(a) | ((unsigned)f2bf(b) << 16);
}
// single-instruction truncating pack (hot path: P) — v_perm_b32
__device__ __forceinline__ unsigned pkt(float a, float b) {
    union { float f; unsigned u; } ca, cb; ca.f = a; cb.f = b;
    return __builtin_amdgcn_perm(cb.u, ca.u, 0x07060302u);  // [bf(b) : bf(a)]
}

// ---------------------------------------------------------------------------
// Prepass: fragment-major bf16 tile images, 4096 u16 per (hd,kt):
//   K''[kc][key][8] : kc = d>>3   (linear = kc*512 + key*8 + e)
//   V''[kc][d][8]   : kc = key>>3 (linear = kc*512 + d*8 + e)
// LDS transpose staging so BOTH sides are contiguous:
//   read:  coalesced float4 row reads of K,V (256B/row-segment, 4 rows/instr)
//   LDS:   [64][33] u32 (bf16 pairs); +1 pad -> column reads are 2-way max
//   write: consecutive lanes -> consecutive uint4 (1KB contiguous per wave)
// Emitted bytes are bit-identical to the previous prepack (same pk2 RNE).
// ---------------------------------------------------------------------------
__global__ __launch_bounds__(256) void prepack(
    const float* __restrict__ k, const float* __restrict__ v,
    unsigned short* __restrict__ kp, unsigned short* __restrict__ vtp)
{
    __shared__ unsigned sK[64 * 33];
    __shared__ unsigned sV[64 * 33];

    const int t  = threadIdx.x;
    const int kt = blockIdx.x, hd = blockIdx.y;
    const size_t tb = ((size_t)hd * NT_ + kt) * 4096;
    uint4* gk = (uint4*)(kp + tb);
    uint4* gv = (uint4*)(vtp + tb);

    // ---- load phase: coalesced row reads, bf16-pack into LDS ----
    #pragma unroll
    for (int i = 0; i < 4; ++i) {
        int n   = t + 256 * i;          // float4 slot 0..1023
        int row = n >> 4, c4 = n & 15;  // row 0..63, 16 float4 per row
        size_t off = (size_t)(kt * 64 + row) * H_ + hd * 64 + c4 * 4;
        {
            float4 a = *(const float4*)(k + off);
            sK[row * 33 + c4 * 2]     = pk2(a.x, a.y);
            sK[row * 33 + c4 * 2 + 1] = pk2(a.z, a.w);
        }
        {
            float4 a = *(const float4*)(v + off);
            sV[row * 33 + c4 * 2]     = pk2(a.x, a.y);
            sV[row * 33 + c4 * 2 + 1] = pk2(a.z, a.w);
        }
    }
    __syncthreads();

    // ---- write phase: gather from LDS, fully-coalesced uint4 stores ----
    #pragma unroll
    for (int i = 0; i < 2; ++i) {
        int o = t + 256 * i;            // uint4 slot 0..511
        {   // K'': o = kc*64 + key ; u16 e: K[key][kc*8+e]
            int kc = o >> 6, key = o & 63;
            uint4 w;
            w.x = sK[key * 33 + kc * 4];
            w.y = sK[key * 33 + kc * 4 + 1];
            w.z = sK[key * 33 + kc * 4 + 2];
            w.w = sK[key * 33 + kc * 4 + 3];
            gk[o] = w;
        }
        {   // V'': o = kc*64 + d ; u16 e: V[kc*8+e][d]
            int kc = o >> 6, d = o & 63;
            int dp = d >> 1, sh = (d & 1) * 16;
            unsigned q[8];
            #pragma unroll
            for (int e = 0; e < 8; ++e)
                q[e] = (sV[(kc * 8 + e) * 33 + dp] >> sh) & 0xffffu;
            uint4 w;
            w.x = q[0] | (q[1] << 16);
            w.y = q[2] | (q[3] << 16);
            w.z = q[4] | (q[5] << 16);
            w.w = q[6] | (q[7] << 16);
            gv[o] = w;
        }
    }
}

// ---------------------------------------------------------------------------
// Main: 256 threads = 4 waves; wave (qg = w>>1, kh = w&1) owns 64 qrows x
// 32-key half (two 32-row groups s=0,1 sharing the SAME K/V fragment loads
// -> 64 FLOP/byte from L2). 128 qrows/block, 512 blocks = exactly 2
// blocks/CU, all resident. Zero barriers in the K-loop; register
// double-buffer of K+V fragments; v_permlane32_swap_b32 exchange.
// (identical to the round-3 passing kernel)
// ---------------------------------------------------------------------------
__global__ __launch_bounds__(256, 2) void attn_main(
    const float* __restrict__ q,
    const unsigned short* __restrict__ kp,
    const unsigned short* __restrict__ vtp,
    float* __restrict__ out)
{
    __shared__ __align__(16) float sO[4 * 2048];   // kh=1 partials, per (qg,s)
    __shared__ float sL[2 * 128];

    const int t   = threadIdx.x;
    const int b   = blockIdx.x;
    // XCD swizzle: 2 heads per XCD (2MB of K''+V'' resident per 4MB L2)
    const int xcd = b & 7;
    const int bi  = b >> 3;                 // 0..63
    const int hd  = xcd * 2 + (bi >> 5);
    const int qt  = bi & 31;                // 32 q-tiles of 128 rows

    const int w    = t >> 6;                // 0..3
    const int lane = t & 63;
    const int l31  = lane & 31;
    const int lhi  = lane >> 5;
    const int qg   = w >> 1;                // 0..1 (64-row q group)
    const int kh   = w & 1;

    const unsigned short* gK = kp  + (size_t)hd * NT_ * 4096;
    const unsigned short* gV = vtp + (size_t)hd * NT_ * 4096;

    // ---- Q fragments (B-operand), scaled, in registers: 2 x 32-row sets ----
    short8 qf[2][4];
    #pragma unroll
    for (int s = 0; s < 2; ++s) {
        const float* qb = q + (size_t)(qt * 128 + qg * 64 + s * 32 + l31) * H_ + hd * 64 + lhi * 8;
        #pragma unroll
        for (int c = 0; c < 4; ++c) {
            float4 a  = *(const float4*)(qb + c * 16);
            float4 bb = *(const float4*)(qb + c * 16 + 4);
            union { short8 v; unsigned u[4]; } f;
            f.u[0] = pk2(a.x * SCALE_LOG2E, a.y * SCALE_LOG2E);
            f.u[1] = pk2(a.z * SCALE_LOG2E, a.w * SCALE_LOG2E);
            f.u[2] = pk2(bb.x * SCALE_LOG2E, bb.y * SCALE_LOG2E);
            f.u[3] = pk2(bb.z * SCALE_LOG2E, bb.w * SCALE_LOG2E);
            qf[s][c] = f.v;
        }
    }

    f32x16 Oacc[2][2];
    #pragma unroll
    for (int s = 0; s < 2; ++s)
        #pragma unroll
        for (int h = 0; h < 2; ++h)
            #pragma unroll
            for (int r = 0; r < 16; ++r) Oacc[s][h][r] = 0.0f;
    float2 ls[2];
    ls[0].x = 0.0f; ls[0].y = 0.0f; ls[1].x = 0.0f; ls[1].y = 0.0f;

    // loop-invariant zero C-operand (init'd once, not per tile)
    f32x16 zero16;
    #pragma unroll
    for (int r = 0; r < 16; ++r) zero16[r] = 0.0f;

    // lane-invariant element offsets into a tile (u16 units)
    const int kOff = (kh * 32 + l31) * 8 + lhi * 512;     // + c*1024
    const int vOff = l31 * 8 + (kh * 4 + lhi) * 512;      // + c*1024 + h*256
    const unsigned short* pK = gK + kOff;
    const unsigned short* pV = gV + vOff;

    short8 kfA[4], vfA[4], kfB[4], vfB[4];

#define LOADF(KF, VF, tile)                                                  \
    {                                                                        \
        const unsigned short* kt_ = pK + (size_t)(tile) * 4096;              \
        const unsigned short* vt_ = pV + (size_t)(tile) * 4096;              \
        KF[0] = *(const short8*)(kt_);                                       \
        KF[1] = *(const short8*)(kt_ + 1024);                                \
        KF[2] = *(const short8*)(kt_ + 2048);                                \
        KF[3] = *(const short8*)(kt_ + 3072);                                \
        VF[0] = *(const short8*)(vt_);                                       \
        VF[1] = *(const short8*)(vt_ + 256);                                 \
        VF[2] = *(const short8*)(vt_ + 1024);                                \
        VF[3] = *(const short8*)(vt_ + 1280);                                \
    }

// softmax of one s-group: 16 exp2 + lsum + trunc-pack
#define SMAX(ST, LS, PU)                                                     \
    {                                                                        \
        _Pragma("unroll")                                                    \
        for (int i2_ = 0; i2_ < 8; ++i2_) {                                  \
            float p0 = __builtin_amdgcn_exp2f(ST[2 * i2_]);                  \
            float p1 = __builtin_amdgcn_exp2f(ST[2 * i2_ + 1]);              \
            LS.x += p0; LS.y += p1;                                          \
            PU[i2_] = pkt(p0, p1);                                           \
        }                                                                    \
    }

// PV of one s-group: permlane exchange + 4 MFMA
#define PVAC(PU, VF, OA)                                                     \
    {                                                                        \
        _Pragma("unroll")                                                    \
        for (int c_ = 0; c_ < 2; ++c_) {                                     \
            unsigned a0 = PU[4 * c_],     b0 = PU[4 * c_ + 2];               \
            unsigned a1 = PU[4 * c_ + 1], b1 = PU[4 * c_ + 3];               \
            /* a' = {a.lo, b.lo}; b' = {a.hi, b.hi} */                       \
            asm("v_permlane32_swap_b32 %0, %1" : "+v"(a0), "+v"(b0));        \
            asm("v_permlane32_swap_b32 %0, %1" : "+v"(a1), "+v"(b1));        \
            union { short8 v; unsigned u[4]; } pf;                           \
            pf.u[0] = a0; pf.u[1] = a1; pf.u[2] = b0; pf.u[3] = b1;          \
            OA[0] = __builtin_amdgcn_mfma_f32_32x32x16_bf16(pf.v, VF[2 * c_],     OA[0], 0, 0, 0); \
            OA[1] = __builtin_amdgcn_mfma_f32_32x32x16_bf16(pf.v, VF[2 * c_ + 1], OA[1], 0, 0, 0); \
        }                                                                    \
    }

#define COMPUTE(KF, VF)                                                      \
    {                                                                        \
        /* both QK chains interleaved: independent work back-to-back */      \
        f32x16 st0 = __builtin_amdgcn_mfma_f32_32x32x16_bf16(KF[0], qf[0][0], zero16, 0, 0, 0); \
        f32x16 st1 = __builtin_amdgcn_mfma_f32_32x32x16_bf16(KF[0], qf[1][0], zero16, 0, 0, 0); \
        st0 = __builtin_amdgcn_mfma_f32_32x32x16_bf16(KF[1], qf[0][1], st0, 0, 0, 0); \
        st1 = __builtin_amdgcn_mfma_f32_32x32x16_bf16(KF[1], qf[1][1], st1, 0, 0, 0); \
        st0 = __builtin_amdgcn_mfma_f32_32x32x16_bf16(KF[2], qf[0][2], st0, 0, 0, 0); \
        st1 = __builtin_amdgcn_mfma_f32_32x32x16_bf16(KF[2], qf[1][2], st1, 0, 0, 0); \
        st0 = __builtin_amdgcn_mfma_f32_32x32x16_bf16(KF[3], qf[0][3], st0, 0, 0, 0); \
        st1 = __builtin_amdgcn_mfma_f32_32x32x16_bf16(KF[3], qf[1][3], st1, 0, 0, 0); \
        unsigned pu0[8], pu1[8];                                             \
        SMAX(st0, ls[0], pu0);                                               \
        PVAC(pu0, VF, Oacc[0]);                                              \
        SMAX(st1, ls[1], pu1);                                               \
        PVAC(pu1, VF, Oacc[1]);                                              \
    }

    // ---- software-pipelined K-loop: prefetch tile t+1 while computing t ----
    LOADF(kfA, vfA, 0);
    for (int kt2 = 0; kt2 < 31; ++kt2) {
        LOADF(kfB, vfB, 2 * kt2 + 1);
        COMPUTE(kfA, vfA);
        LOADF(kfA, vfA, 2 * kt2 + 2);
        COMPUTE(kfB, vfB);
    }
    LOADF(kfB, vfB, 63);
    COMPUTE(kfA, vfA);
    COMPUTE(kfB, vfB);

#undef LOADF
#undef SMAX
#undef PVAC
#undef COMPUTE

    // ---- epilogue: combine kh halves, normalize, store ----
    #pragma unroll
    for (int s = 0; s < 2; ++s) {
        float lsum = ls[s].x + ls[s].y;
        lsum += __shfl_xor(lsum, 32);
        if (lhi == 0) sL[kh * 128 + qg * 64 + s * 32 + l31] = lsum;
    }
    if (kh == 1) {
        #pragma unroll
        for (int s = 0; s < 2; ++s) {
            float* o = sO + (qg * 2 + s) * 2048;
            #pragma unroll
            for (int h = 0; h < 2; ++h)
                #pragma unroll
                for (int r = 0; r < 16; ++r)
                    o[h * 1024 + r * 64 + lane] = Oacc[s][h][r];
        }
    }
    __syncthreads();
    if (kh == 0) {
        #pragma unroll
        for (int s = 0; s < 2; ++s) {
            float linv[4][4];
            #pragma unroll
            for (int qd = 0; qd < 4; ++qd) {
                int base = qg * 64 + s * 32 + 8 * qd + 4 * lhi;
                float4 a  = *(const float4*)(sL + base);
                float4 bb = *(const float4*)(sL + 128 + base);
                linv[qd][0] = __builtin_amdgcn_rcpf(a.x + bb.x);
                linv[qd][1] = __builtin_amdgcn_rcpf(a.y + bb.y);
                linv[qd][2] = __builtin_amdgcn_rcpf(a.z + bb.z);
                linv[qd][3] = __builtin_amdgcn_rcpf(a.w + bb.w);
            }
            const float* o = sO + (qg * 2 + s) * 2048;
            #pragma unroll
            for (int h = 0; h < 2; ++h)
                #pragma unroll
                for (int qd = 0; qd < 4; ++qd)
                    #pragma unroll
                    for (int e = 0; e < 4; ++e) {
                        int r   = 4 * qd + e;
                        int row = e + 8 * qd + 4 * lhi;
                        float val = (Oacc[s][h][r] + o[h * 1024 + r * 64 + lane]) * linv[qd][e];
                        out[(size_t)(qt * 128 + qg * 64 + s * 32 + row) * H_ + hd * 64 + h * 32 + l31] = val;
                    }
        }
    }
}

extern "C" void kernel_launch(void* const* d_in, const int* in_sizes, int n_in,
                              void* d_out, int out_size, void* d_ws, size_t ws_size,
                              hipStream_t stream) {
    const float* q = (const float*)d_in[0];
    const float* k = (const float*)d_in[1];
    const float* v = (const float*)d_in[2];
    float* out = (float*)d_out;

    unsigned short* kp  = (unsigned short*)d_ws;                 // 8 MB
    unsigned short* vtp = kp + (size_t)NH_ * NT_ * 4096;         // 8 MB

    prepack<<<dim3(NT_, NH_), 256, 0, stream>>>(k, v, kp, vtp);
    attn_main<<<dim3(512), 256, 0, stream>>>(q, kp, vtp, out);
}